// Round 4
// baseline (182.300 us; speedup 1.0000x reference)
//
#include <hip/hip_runtime.h>
#include <cmath>

#define ENTRIES 27
#define ACTION  4096
#define BATCH   8192
#define SDIM    322
#define KPAD    360      // 322 padded; stride 720B -> ~2-way LDS conflict (free)
#define NNODES  256

typedef unsigned short u16;
typedef u16 u16x4 __attribute__((ext_vector_type(4)));
typedef u16 u16x8 __attribute__((ext_vector_type(8)));
typedef __bf16 bf16x8 __attribute__((ext_vector_type(8)));
typedef float floatx2 __attribute__((ext_vector_type(2)));
typedef float floatx4 __attribute__((ext_vector_type(4)));

__device__ __forceinline__ u16 f2bf(float f) {
    unsigned u = __builtin_bit_cast(unsigned, f);
    unsigned r = (u + 0x7FFFu + ((u >> 16) & 1u)) >> 16;   // RNE
    return (u16)r;
}
__device__ __forceinline__ float sig500(float v) {
    return __fdividef(500.0f, 1.0f + __expf(-v));
}
__device__ __forceinline__ float ftanh(float x) {
    return 1.0f - __fdividef(2.0f, __expf(2.0f * x) + 1.0f);
}
// async global->LDS, 16 B per lane; LDS dest = wave-uniform base + lane*16
__device__ __forceinline__ void gl_lds16(const u16* g, u16* l) {
    __builtin_amdgcn_global_load_lds(
        (const __attribute__((address_space(1))) unsigned int*)g,
        (__attribute__((address_space(3))) unsigned int*)l, 16, 0, 0);
}

// ---------------------------------------------------------------------------
// K1: y = tanh(state . WgT + b), bf16 out  — prep fully fused, 512 blocks.
//  * prologue A: Wf f32->bf16 (8 elem/thr over 512 blocks) -> wfb for K2
//    (K2 launches after K1; stream order guarantees visibility)
//  * prologue B: build this block's 64-row Wg slice DIRECTLY IN LDS:
//    8-row f32 scratch {zero -> atomicAdd scatter from (W,idx) -> cvt to Bs}
//    x8.  No global wg buffer, no prep kernel.
//  * main loop: verified round-2 structure — A=state converted in regs
//    (loads fly under MFMA), B LDS-resident, 2x2 waves of 32x32.
// LDS: Bs 46080 + (scratch 11520 ∪ As 4096) = 57600 B -> 2 blocks/CU.
// ---------------------------------------------------------------------------
__global__ __launch_bounds__(256) void gemm1_all(
    const float* __restrict__ state, const float* __restrict__ W,
    const float* __restrict__ bias,  const float* __restrict__ Wf,
    const int*   __restrict__ idx,
    u16* __restrict__ wfb, u16* __restrict__ y)
{
    __shared__ u16 lds[28800];          // 57600 B
    u16*   Bs      = lds;               // [64][KPAD] bf16 = 46080 B
    u16*   As      = lds + 64 * KPAD;   // [64][32] bf16 = 4096 B (main loop)
    float* scratch = (float*)(lds + 64 * KPAD);   // 8*KPAD f32 = 11520 B (build)

    const int tid  = threadIdx.x;
    const int bid  = blockIdx.x;
    const int lane = tid & 63;
    const int wave = tid >> 6;
    const int wm   = wave & 1;
    const int wn   = wave >> 1;
    const int l15  = lane & 15;
    const int koff = (lane >> 4) << 3;
    const int bm   = bid & 127;         // 128 row-tiles of 64
    const int bn   = bid >> 7;          // 4 node-tiles of 64

    // ---- prologue A: Wf f32 -> bf16 (independent; consumed by K2) ----
    {
        const int i0 = (bid * 256 + tid) * 8;     // 512*256*8 = 4096*256
        floatx4 v0 = *(const floatx4*)(Wf + i0);
        floatx4 v1 = *(const floatx4*)(Wf + i0 + 4);
        u16x8 r;
        r[0] = f2bf(v0.x); r[1] = f2bf(v0.y); r[2] = f2bf(v0.z); r[3] = f2bf(v0.w);
        r[4] = f2bf(v1.x); r[5] = f2bf(v1.y); r[6] = f2bf(v1.z); r[7] = f2bf(v1.w);
        *(u16x8*)(wfb + i0) = r;
    }

    // ---- prologue B: build Wg slice [64][KPAD] bf16 into Bs, 8 rows/pass ----
    for (int g = 0; g < 8; g++) {
        for (int i = tid; i < 8 * KPAD; i += 256) scratch[i] = 0.f;
        __syncthreads();
        if (tid < 8 * ENTRIES) {                        // 216 active
            const int nl = tid / ENTRIES;
            const int e  = tid - nl * ENTRIES;
            const int n  = bn * 64 + g * 8 + nl;
            atomicAdd(&scratch[nl * KPAD + idx[n * ENTRIES + e]],
                      W[n * ENTRIES + e]);
        }
        __syncthreads();
        for (int i = tid; i < 8 * KPAD; i += 256)
            Bs[g * 8 * KPAD + i] = f2bf(scratch[i]);
        __syncthreads();   // cvt reads scratch before next pass zeroes it
    }

    // ---- A register prefetch: thread -> (row = tid>>2, 8 cols) ----
    const int arow = tid >> 2;
    const int qseg = tid & 3;
    const float* ap = state + (size_t)(bm * 64 + arow) * SDIM + qseg * 8;
    float va[8];
    auto loada = [&](int kk) {
        const int c0 = kk + qseg * 8;
        const float* p = ap + kk;
        if (c0 + 8 <= SDIM) {
#pragma unroll
            for (int j = 0; j < 4; j++)
                *(floatx2*)&va[2 * j] = *(const floatx2*)(p + 2 * j);
        } else {
#pragma unroll
            for (int j = 0; j < 8; j++)
                va[j] = (c0 + j < SDIM) ? p[j] : 0.f;   // zero-pad tail
        }
    };
    loada(0);

    floatx4 acc[2][2];
#pragma unroll
    for (int mi = 0; mi < 2; mi++)
#pragma unroll
        for (int ni = 0; ni < 2; ni++)
            acc[mi][ni] = (floatx4){0.f, 0.f, 0.f, 0.f};

#pragma unroll
    for (int s = 0; s < 11; s++) {
        const int kk = s * 32;
        u16x8 pk;                          // cvt prefetched A (vmcnt waits here)
#pragma unroll
        for (int j = 0; j < 8; j++) ((u16*)&pk)[j] = f2bf(va[j]);

        __syncthreads();                   // prev iter's ds_reads done
        *(u16x8*)&As[arow * 32 + qseg * 8] = pk;
        __syncthreads();                   // As(k) visible

        if (s < 10) loada(kk + 32);        // next loads fly under MFMA

        bf16x8 af[2], bfr[2];
#pragma unroll
        for (int mi = 0; mi < 2; mi++)
            af[mi] = __builtin_bit_cast(bf16x8,
                *(const u16x8*)&As[((wm << 5) + (mi << 4) + l15) * 32 + koff]);
#pragma unroll
        for (int ni = 0; ni < 2; ni++)
            bfr[ni] = __builtin_bit_cast(bf16x8,
                *(const u16x8*)&Bs[(wn * 32 + ni * 16 + l15) * KPAD + kk + koff]);
#pragma unroll
        for (int mi = 0; mi < 2; mi++)
#pragma unroll
            for (int ni = 0; ni < 2; ni++)
                acc[mi][ni] = __builtin_amdgcn_mfma_f32_16x16x32_bf16(
                    af[mi], bfr[ni], acc[mi][ni], 0, 0, 0);
    }

    // epilogue: C/D layout col=lane&15, row=(lane>>4)*4+reg
    const int r0 = (lane >> 4) << 2;
    float bv[2];
#pragma unroll
    for (int ni = 0; ni < 2; ni++)
        bv[ni] = bias[bn * 64 + wn * 32 + ni * 16 + l15];
#pragma unroll
    for (int mi = 0; mi < 2; mi++)
#pragma unroll
        for (int ni = 0; ni < 2; ni++) {
            const int row = bm * 64 + wm * 32 + mi * 16 + r0;
            const int col = bn * 64 + wn * 32 + ni * 16 + l15;
#pragma unroll
            for (int r = 0; r < 4; r++)
                y[(size_t)(row + r) * NNODES + col] =
                    f2bf(ftanh(acc[mi][ni][r] + bv[ni]));
        }
}

// ---------------------------------------------------------------------------
// K2 (verified m97 structure, unchanged): out = 500*sigmoid(y . WfT)
// Tile 128x128, BK=32, 4 waves 2x2, global_load_lds width-16 staging.
// Write-bound: 134 MB f32 output.
// ---------------------------------------------------------------------------
__global__ __launch_bounds__(256) void gemm2(
    const u16* __restrict__ A, const u16* __restrict__ B,
    float* __restrict__ out)
{
    __shared__ u16 As[128 * 32];
    __shared__ u16 Bs[128 * 32];

    const int bm   = blockIdx.x;
    const int bn   = blockIdx.y;
    const int tid  = threadIdx.x;
    const int lane = tid & 63;
    const int wave = tid >> 6;
    const int wm   = wave & 1;
    const int wn   = wave >> 1;
    const int l15  = lane & 15;
    const int koff = (lane >> 4) << 3;

    floatx4 acc[4][4];
#pragma unroll
    for (int mi = 0; mi < 4; mi++)
#pragma unroll
        for (int ni = 0; ni < 4; ni++)
            acc[mi][ni] = (floatx4){0.f, 0.f, 0.f, 0.f};

    const int crow = lane >> 2;
    const int ckel = (lane & 3) << 3;

#pragma unroll
    for (int kk = 0; kk < 256; kk += 32) {
        __syncthreads();
#pragma unroll
        for (int c = wave; c < 16; c += 4) {
            const bool isA = c < 8;
            const int  cr  = isA ? c : c - 8;
            const int  row = cr * 16 + crow;
            const u16* g = isA
                ? (A + ((size_t)bm * 128 + row) * 256 + kk + ckel)
                : (B + ((size_t)bn * 128 + row) * 256 + kk + ckel);
            gl_lds16(g, isA ? &As[cr * 512] : &Bs[cr * 512]);
        }
        __syncthreads();

        bf16x8 af[4], bfg[4];
#pragma unroll
        for (int mi = 0; mi < 4; mi++)
            af[mi] = __builtin_bit_cast(bf16x8,
                *(const u16x8*)&As[((wm << 6) + (mi << 4) + l15) * 32 + koff]);
#pragma unroll
        for (int ni = 0; ni < 4; ni++)
            bfg[ni] = __builtin_bit_cast(bf16x8,
                *(const u16x8*)&Bs[(wn * 64 + (ni << 4) + l15) * 32 + koff]);

#pragma unroll
        for (int mi = 0; mi < 4; mi++)
#pragma unroll
            for (int ni = 0; ni < 4; ni++)
                acc[mi][ni] = __builtin_amdgcn_mfma_f32_16x16x32_bf16(
                    af[mi], bfg[ni], acc[mi][ni], 0, 0, 0);
    }

    const int r0 = (lane >> 4) << 2;
#pragma unroll
    for (int mi = 0; mi < 4; mi++)
#pragma unroll
        for (int ni = 0; ni < 4; ni++) {
            const int row = bm * 128 + wm * 64 + mi * 16 + r0;
            const int col = bn * 128 + wn * 64 + ni * 16 + l15;
#pragma unroll
            for (int r = 0; r < 4; r++)
                out[(size_t)(row + r) * ACTION + col] = sig500(acc[mi][ni][r]);
        }
}

extern "C" void kernel_launch(void* const* d_in, const int* in_sizes, int n_in,
                              void* d_out, int out_size, void* d_ws, size_t ws_size,
                              hipStream_t stream) {
    const float* state = (const float*)d_in[0];
    const float* W     = (const float*)d_in[1];
    const float* b     = (const float*)d_in[2];
    const float* Wf    = (const float*)d_in[3];
    const int*   idx   = (const int*)  d_in[4];
    float* out = (float*)d_out;

    u16* wfb = (u16*)d_ws;                         // 4096*256 bf16
    u16* y   = wfb + (size_t)ACTION * NNODES;      // 8192*256 bf16

    gemm1_all<<<512, 256, 0, stream>>>(state, W, b, Wf, idx, wfb, y);
    gemm2<<<dim3(BATCH / 128, ACTION / 128), 256, 0, stream>>>(y, wfb, out);
}